// Round 4
// baseline (504.328 us; speedup 1.0000x reference)
//
#include <hip/hip_runtime.h>

// C[b,i] = 0.125 * sum_k LI[X[b,8,3]][k] * IL[i][k]
// M=1024, N=100000, K=64.  Write-bound (409.6 MB out).
//
// v3: phase-1a gathers A=bf16(LI[X[:,8,3]]) (128 KB); phase-1b converts IL to
// bf16 once (12.8 MB in ws) -> phase-2 streams pre-converted bf16 B fragments
// straight to MFMA (no convert chain), A-fragments hoisted to regs (LDS read
// once), b double-buffered across chunks.  Inner loop = 4 loads + 16 MFMA + 8 NT stores.

typedef short short8 __attribute__((ext_vector_type(8)));
typedef float f32x4 __attribute__((ext_vector_type(4)));
typedef unsigned short ushort4v __attribute__((ext_vector_type(4)));
typedef unsigned short ushort8v __attribute__((ext_vector_type(8)));

#define KDIM  64
#define LDSS  72     // LDS row stride in bf16 (144 B -> 2-way bank alias only, free)
#define MSLAB 256
#define NSLAB 256
#define NCH   32

static __device__ __forceinline__ unsigned short f2bf(float f) {
    unsigned u = __float_as_uint(f);
    return (unsigned short)((u + 0x7fffu + ((u >> 16) & 1u)) >> 16);   // RNE
}

static __device__ __forceinline__ short8 cvt8(float4 v0, float4 v1) {
    union { ushort8v u; short8 s; } r;
    r.u[0] = f2bf(v0.x); r.u[1] = f2bf(v0.y); r.u[2] = f2bf(v0.z); r.u[3] = f2bf(v0.w);
    r.u[4] = f2bf(v1.x); r.u[5] = f2bf(v1.y); r.u[6] = f2bf(v1.z); r.u[7] = f2bf(v1.w);
    return r.s;
}

// ---- Phase 1a: A[b][k] = bf16(LI[X[b,8,3]][k]). 64 blocks. ----
__global__ __launch_bounds__(256)
void fpmc_gather(const int* __restrict__ X, const float* __restrict__ LI,
                 unsigned short* __restrict__ Abf, int M) {
    const int t = threadIdx.x;
    const int r = blockIdx.x * 16 + (t >> 4);
    if (r >= M) return;
    const int c = (t & 15) * 4;
    const int idx = X[r * 40 + 35];                    // X[b, 8, 3]
    const float4 v = *(const float4*)(LI + (size_t)idx * KDIM + c);
    ushort4v p;
    p.x = f2bf(v.x); p.y = f2bf(v.y); p.z = f2bf(v.z); p.w = f2bf(v.w);
    *(ushort4v*)(Abf + (size_t)r * KDIM + c) = p;
}

// ---- Phase 1b: ILbf = bf16(IL), flat 16 elems/thread. ----
__global__ __launch_bounds__(256)
void fpmc_cvt(const float* __restrict__ IL, unsigned short* __restrict__ ILbf,
              int total) {
    const int tid = blockIdx.x * 256 + threadIdx.x;
    const int base = tid * 16;
    if (base >= total) return;
    const float4* src = (const float4*)(IL + base);
    ushort8v* dst = (ushort8v*)(ILbf + base);
    union { ushort8v u; short8 s; } a, b;
    a.s = cvt8(src[0], src[1]);
    b.s = cvt8(src[2], src[3]);
    dst[0] = a.u;
    dst[1] = b.u;
}

// ---- Phase 2.  MODE 2: bf16 IL + ws A; MODE 1: fp32 IL + ws A; MODE 0: self-gather. ----
template<int MODE>
__global__ __launch_bounds__(256, 4)
void fpmc_gemm3(const int* __restrict__ X, const float* __restrict__ IL,
                const float* __restrict__ LI, const unsigned short* __restrict__ ILbf,
                const unsigned short* __restrict__ Abf,
                float* __restrict__ out, int M, int N) {
    __shared__ __align__(16) unsigned short As[MSLAB * LDSS];   // 36,864 B -> 4 blocks/CU

    const int t  = threadIdx.x;
    const int m0 = blockIdx.y * MSLAB;
    const int i0 = blockIdx.x * NSLAB;

    if (MODE >= 1) {
        #pragma unroll
        for (int it = 0; it < 8; ++it) {
            const int chunk = it * 256 + t;
            const int r = chunk >> 3;
            const int c = (chunk & 7) * 8;
            ushort8v v = *(const ushort8v*)(Abf + (size_t)(m0 + r) * KDIM + c);
            *(ushort8v*)&As[r * LDSS + c] = v;
        }
    } else {
        const int rb = t >> 4;
        const int c  = (t & 15) * 4;
        #pragma unroll
        for (int it = 0; it < MSLAB / 16; ++it) {
            const int r = it * 16 + rb;
            const int idx = X[(m0 + r) * 40 + 35];
            const float4 v = *(const float4*)(LI + (size_t)idx * KDIM + c);
            ushort4v p;
            p.x = f2bf(v.x); p.y = f2bf(v.y); p.z = f2bf(v.z); p.w = f2bf(v.w);
            *(ushort4v*)&As[r * LDSS + c] = p;
        }
    }
    __syncthreads();

    const int w    = t >> 6;
    const int l    = t & 63;
    const int lr   = l & 15;
    const int quad = l >> 4;
    const int mwav = w * 64;
    const float scale = 0.125f;

    // hoist A fragments: nc-invariant, read LDS once. a[ks][mt], 32 VGPR.
    short8 a[2][4];
    #pragma unroll
    for (int ks = 0; ks < 2; ++ks)
        #pragma unroll
        for (int mt = 0; mt < 4; ++mt)
            a[ks][mt] = *(const short8*)&As[(mwav + mt * 16 + lr) * LDSS + ks * 32 + quad * 8];

    // b fragment loader: b[ks][nt]
    auto loadB = [&](int nc, short8 b[2][2]) {
        const int n0c = i0 + nc * NCH;
        #pragma unroll
        for (int nt = 0; nt < 2; ++nt) {
            int n = n0c + nt * 16 + lr;
            if (n > N - 1) n = N - 1;                  // clamp; stores guarded below
            if (MODE == 2) {
                const ushort8v* p = (const ushort8v*)(ILbf + (size_t)n * KDIM);
                union { ushort8v u; short8 s; } r0, r1;
                r0.u = p[quad];            // ks=0: cols quad*8..+7
                r1.u = p[4 + quad];        // ks=1: cols 32+quad*8..+7
                b[0][nt] = r0.s;
                b[1][nt] = r1.s;
            } else {
                const float* p = IL + (size_t)n * KDIM + quad * 8;
                b[0][nt] = cvt8(*(const float4*)p, *(const float4*)(p + 4));
                b[1][nt] = cvt8(*(const float4*)(p + 32), *(const float4*)(p + 36));
            }
        }
    };

    short8 bc[2][2], bn[2][2];
    loadB(0, bc);

    #pragma unroll 1
    for (int nc = 0; nc < NSLAB / NCH; ++nc) {
        if (nc + 1 < NSLAB / NCH) loadB(nc + 1, bn);   // prefetch next chunk

        f32x4 acc[4][2];
        #pragma unroll
        for (int mt = 0; mt < 4; ++mt)
            #pragma unroll
            for (int nt = 0; nt < 2; ++nt)
                acc[mt][nt] = (f32x4){0.f, 0.f, 0.f, 0.f};

        #pragma unroll
        for (int ks = 0; ks < 2; ++ks)
            #pragma unroll
            for (int mt = 0; mt < 4; ++mt)
                #pragma unroll
                for (int nt = 0; nt < 2; ++nt)
                    acc[mt][nt] = __builtin_amdgcn_mfma_f32_16x16x32_bf16(
                        bc[ks][nt], a[ks][mt], acc[mt][nt], 0, 0, 0);

        const int n0c = i0 + nc * NCH;
        #pragma unroll
        for (int mt = 0; mt < 4; ++mt) {
            const int m = m0 + mwav + mt * 16 + lr;
            float* orow = out + (size_t)m * N;
            #pragma unroll
            for (int nt = 0; nt < 2; ++nt) {
                const int n = n0c + nt * 16 + quad * 4;
                if (n < N) {
                    f32x4 v = acc[mt][nt] * scale;
                    __builtin_nontemporal_store(v, (f32x4*)(orow + n));
                }
            }
        }

        #pragma unroll
        for (int ks = 0; ks < 2; ++ks)
            #pragma unroll
            for (int nt = 0; nt < 2; ++nt)
                bc[ks][nt] = bn[ks][nt];
    }
}

extern "C" void kernel_launch(void* const* d_in, const int* in_sizes, int n_in,
                              void* d_out, int out_size, void* d_ws, size_t ws_size,
                              hipStream_t stream) {
    const int*   X  = (const int*)d_in[0];
    const float* IL = (const float*)d_in[1];
    const float* LI = (const float*)d_in[2];
    float* out = (float*)d_out;

    const int M = in_sizes[0] / 40;      // 1024
    const int N = in_sizes[1] / KDIM;    // 100000

    const size_t ilbf_bytes = (size_t)N * KDIM * sizeof(unsigned short);   // 12.8 MB
    const size_t a_bytes    = (size_t)M * KDIM * sizeof(unsigned short);   // 128 KB

    unsigned short* ILbf = (unsigned short*)d_ws;
    unsigned short* Abf  = (unsigned short*)((char*)d_ws + ilbf_bytes);

    dim3 grid((N + NSLAB - 1) / NSLAB, (M + MSLAB - 1) / MSLAB);

    if (d_ws != nullptr && ws_size >= ilbf_bytes + a_bytes) {
        const int total = N * KDIM;
        fpmc_gather<<<dim3((M + 15) / 16), dim3(256), 0, stream>>>(X, LI, Abf, M);
        fpmc_cvt<<<dim3((total / 16 + 255) / 256), dim3(256), 0, stream>>>(IL, ILbf, total);
        fpmc_gemm3<2><<<grid, dim3(256), 0, stream>>>(X, IL, LI, ILbf, Abf, out, M, N);
    } else if (d_ws != nullptr && ws_size >= a_bytes) {
        unsigned short* A0 = (unsigned short*)d_ws;
        fpmc_gather<<<dim3((M + 15) / 16), dim3(256), 0, stream>>>(X, LI, A0, M);
        fpmc_gemm3<1><<<grid, dim3(256), 0, stream>>>(X, IL, LI, nullptr, A0, out, M, N);
    } else {
        fpmc_gemm3<0><<<grid, dim3(256), 0, stream>>>(X, IL, LI, nullptr, nullptr, out, M, N);
    }
}

// Round 5
// 495.194 us; speedup vs baseline: 1.0184x; 1.0184x over previous
//
#include <hip/hip_runtime.h>

// C[b,i] = 0.125 * sum_k LI[X[b,8,3]][k] * IL[i][k]
// M=1024, N=100000, K=64.  Write-bound (409.6 MB out).
//
// v4 "row-streamer": write locality is the lever.  Block = 8 waves owning
// 16 m-rows x 12544 n-cols -> 50 KB contiguous per row, 8K chip-wide write
// streams (was 400K).  Waves interleave adjacent 32-col chunks so full 128B
// lines assemble in L2 from back-to-back stores.  A in registers (no LDS, no
// barriers); B = pre-converted bf16 IL, 2-deep prefetch; plain (cached) stores.
// 1-D grid decoded bx=b&7 -> each XCD owns one IL column-slab (L2-resident).

typedef short short8 __attribute__((ext_vector_type(8)));
typedef float f32x4 __attribute__((ext_vector_type(4)));
typedef unsigned short ushort4v __attribute__((ext_vector_type(4)));
typedef unsigned short ushort8v __attribute__((ext_vector_type(8)));

#define KDIM   64
#define MROWS  16
#define NWAVES 8
#define NCHUNK 32
#define JCH    49
#define NBLK   (NWAVES * JCH * NCHUNK)   // 12544 cols per block

static __device__ __forceinline__ unsigned short f2bf(float f) {
    unsigned u = __float_as_uint(f);
    return (unsigned short)((u + 0x7fffu + ((u >> 16) & 1u)) >> 16);   // RNE
}

static __device__ __forceinline__ short8 cvt8(float4 v0, float4 v1) {
    union { ushort8v u; short8 s; } r;
    r.u[0] = f2bf(v0.x); r.u[1] = f2bf(v0.y); r.u[2] = f2bf(v0.z); r.u[3] = f2bf(v0.w);
    r.u[4] = f2bf(v1.x); r.u[5] = f2bf(v1.y); r.u[6] = f2bf(v1.z); r.u[7] = f2bf(v1.w);
    return r.s;
}

// ---- Phase 1 (fused): blocks [0,cvtBlocks) convert IL->bf16; rest gather A. ----
__global__ __launch_bounds__(256)
void fpmc_prep(const int* __restrict__ X, const float* __restrict__ IL,
               const float* __restrict__ LI, unsigned short* __restrict__ ILbf,
               unsigned short* __restrict__ Abf, int M, int total, int cvtBlocks) {
    const int b = blockIdx.x;
    const int t = threadIdx.x;
    if (b < cvtBlocks) {
        const int base = (b * 256 + t) * 16;
        if (base < total) {
            const float4* src = (const float4*)(IL + base);
            ushort8v* dst = (ushort8v*)(ILbf + base);
            union { ushort8v u; short8 s; } a0, a1;
            a0.s = cvt8(src[0], src[1]);
            a1.s = cvt8(src[2], src[3]);
            dst[0] = a0.u;
            dst[1] = a1.u;
        }
    } else {
        const int r = (b - cvtBlocks) * 16 + (t >> 4);
        if (r < M) {
            const int c = (t & 15) * 4;
            const int idx = X[r * 40 + 35];            // X[b, 8, 3]
            const float4 v = *(const float4*)(LI + (size_t)idx * KDIM + c);
            ushort4v p;
            p.x = f2bf(v.x); p.y = f2bf(v.y); p.z = f2bf(v.z); p.w = f2bf(v.w);
            *(ushort4v*)(Abf + (size_t)r * KDIM + c) = p;
        }
    }
}

// ---- Phase 2: 16-row stream GEMM.  MODE 1 = ws (bf16 IL + gathered A), MODE 0 = direct. ----
template<int MODE>
__global__ __launch_bounds__(512, 4)
void fpmc_gemm4(const int* __restrict__ X, const float* __restrict__ IL,
                const float* __restrict__ LI, const unsigned short* __restrict__ ILbf,
                const unsigned short* __restrict__ Abf,
                float* __restrict__ out, int M, int N) {
    const int b  = blockIdx.x;
    const int bx = b & 7;            // n-slab: same XCD -> same slab (L2-resident IL)
    const int by = b >> 3;           // m-slab
    const int t    = threadIdx.x;
    const int w    = t >> 6;         // 0..7
    const int l    = t & 63;
    const int lr   = l & 15;
    const int quad = l >> 4;
    const int m0 = by * MROWS;
    const int i0 = bx * NBLK;
    const float scale = 0.125f;

    // A fragments: row m0+lr, k = ks*32 + quad*8 .. +7.  8 VGPR, loaded once.
    short8 a[2];
    if (MODE == 1) {
        const ushort8v* pa = (const ushort8v*)(Abf + (size_t)(m0 + lr) * KDIM);
        union { ushort8v u; short8 s; } r0, r1;
        r0.u = pa[quad];
        r1.u = pa[4 + quad];
        a[0] = r0.s;
        a[1] = r1.s;
    } else {
        const int idx = X[(m0 + lr) * 40 + 35];
        const float* p = LI + (size_t)idx * KDIM + quad * 8;
        a[0] = cvt8(*(const float4*)p,        *(const float4*)(p + 4));
        a[1] = cvt8(*(const float4*)(p + 32), *(const float4*)(p + 36));
    }

    // B loader for this wave's chunk j: rows n0c+nt*16+lr, same k split.
    auto loadB = [&](int j, short8 bq[2][2]) {
        const int n0c = i0 + (j * NWAVES + w) * NCHUNK;
        #pragma unroll
        for (int nt = 0; nt < 2; ++nt) {
            int n = n0c + nt * 16 + lr;
            if (n > N - 1) n = N - 1;                  // clamp; stores guarded below
            if (MODE == 1) {
                const ushort8v* p = (const ushort8v*)(ILbf + (size_t)n * KDIM);
                union { ushort8v u; short8 s; } r0, r1;
                r0.u = p[quad];
                r1.u = p[4 + quad];
                bq[0][nt] = r0.s;
                bq[1][nt] = r1.s;
            } else {
                const float* p = IL + (size_t)n * KDIM + quad * 8;
                bq[0][nt] = cvt8(*(const float4*)p,        *(const float4*)(p + 4));
                bq[1][nt] = cvt8(*(const float4*)(p + 32), *(const float4*)(p + 36));
            }
        }
    };

    short8 bq[3][2][2];              // 2-deep prefetch ring; j fully unrolled -> static idx
    loadB(0, bq[0]);
    loadB(1, bq[1]);

    #pragma unroll
    for (int j = 0; j < JCH; ++j) {
        if (j + 2 < JCH) loadB(j + 2, bq[(j + 2) % 3]);

        f32x4 acc[2];
        acc[0] = (f32x4){0.f, 0.f, 0.f, 0.f};
        acc[1] = (f32x4){0.f, 0.f, 0.f, 0.f};

        #pragma unroll
        for (int ks = 0; ks < 2; ++ks)
            #pragma unroll
            for (int nt = 0; nt < 2; ++nt)
                acc[nt] = __builtin_amdgcn_mfma_f32_16x16x32_bf16(
                    bq[j % 3][ks][nt], a[ks], acc[nt], 0, 0, 0);

        // store: m = m0+lr (16 rows/instr), n = n0c + nt*16 + quad*4 (+reg).
        // plain cached stores: nt=0/1 back-to-back fill each 128B line in L2.
        const int n0c = i0 + (j * NWAVES + w) * NCHUNK;
        float* orow = out + (size_t)(m0 + lr) * N;
        #pragma unroll
        for (int nt = 0; nt < 2; ++nt) {
            const int n = n0c + nt * 16 + quad * 4;
            if (n < N)                                  // N%4==0 -> whole-f32x4 guard
                *(f32x4*)(orow + n) = acc[nt] * scale;
        }
    }
}

extern "C" void kernel_launch(void* const* d_in, const int* in_sizes, int n_in,
                              void* d_out, int out_size, void* d_ws, size_t ws_size,
                              hipStream_t stream) {
    const int*   X  = (const int*)d_in[0];
    const float* IL = (const float*)d_in[1];
    const float* LI = (const float*)d_in[2];
    float* out = (float*)d_out;

    const int M = in_sizes[0] / 40;      // 1024
    const int N = in_sizes[1] / KDIM;    // 100000

    const size_t ilbf_bytes = (size_t)N * KDIM * sizeof(unsigned short);   // 12.8 MB
    const size_t a_bytes    = (size_t)M * KDIM * sizeof(unsigned short);   // 128 KB

    const int gx = (N + NBLK - 1) / NBLK;        // 8
    const int gy = (M + MROWS - 1) / MROWS;      // 64
    dim3 grid(gx * gy);                          // 512 blocks, bx=b&7 (gx==8)

    if (d_ws != nullptr && ws_size >= ilbf_bytes + a_bytes && gx == 8) {
        unsigned short* ILbf = (unsigned short*)d_ws;
        unsigned short* Abf  = (unsigned short*)((char*)d_ws + ilbf_bytes);
        const int total = N * KDIM;
        const int cvtBlocks = (total / 16 + 255) / 256;
        const int gatherBlocks = (M + 15) / 16;
        fpmc_prep<<<dim3(cvtBlocks + gatherBlocks), dim3(256), 0, stream>>>(
            X, IL, LI, ILbf, Abf, M, total, cvtBlocks);
        fpmc_gemm4<1><<<grid, dim3(512), 0, stream>>>(X, IL, LI, ILbf, Abf, out, M, N);
    } else {
        fpmc_gemm4<0><<<grid, dim3(512), 0, stream>>>(X, IL, LI, nullptr, nullptr, out, M, N);
    }
}